// Round 4
// baseline (526.207 us; speedup 1.0000x reference)
//
#include <hip/hip_runtime.h>

typedef unsigned int uint;
typedef unsigned short ushort;

using s16x8 = __attribute__((ext_vector_type(8))) short;
using f32x4 = __attribute__((ext_vector_type(4))) float;

#define NPIX 65536   // 16 * 64 * 64 pixels
#define LDF 640      // feat row stride: 512 (h1) + 25 (gs) + pad to K-tile multiple

// ---------- helpers ----------
__device__ __forceinline__ ushort f2bf(float f) {
    uint u = __float_as_uint(f);
    u += 0x7fffu + ((u >> 16) & 1u);   // RNE
    return (ushort)(u >> 16);
}
__device__ __forceinline__ float bf2f(uint h) { return __uint_as_float(h << 16); }

__device__ __forceinline__ void async16(const void* g, void* l) {
    __builtin_amdgcn_global_load_lds(
        (const __attribute__((address_space(1))) void*)g,
        (__attribute__((address_space(3))) void*)l, 16, 0, 0);
}

// ---------- x (b,c,h,w) fp32 -> xT [n][c] bf16 ----------
__global__ __launch_bounds__(256) void txpose(const float* __restrict__ x, ushort* __restrict__ xT) {
    __shared__ float tile[32][33];
    int t = threadIdx.x, col = t & 31, rq = t >> 5;
    size_t srcBase = ((size_t)blockIdx.z * 1024 + blockIdx.y * 32) * 4096 + blockIdx.x * 32;
#pragma unroll
    for (int r = 0; r < 4; ++r) {
        int row = rq + r * 8;                       // c_local
        tile[row][col] = x[srcBase + (size_t)row * 4096 + col];
    }
    __syncthreads();
    size_t dstBase = ((size_t)blockIdx.z * 4096 + blockIdx.x * 32) * 1024 + blockIdx.y * 32;
#pragma unroll
    for (int r = 0; r < 4; ++r) {
        int row = rq + r * 8;                       // s_local
        xT[dstBase + (size_t)row * 1024 + col] = f2bf(tile[col][row]);
    }
}

// ---------- all three weights fp32 -> bf16 (w_emb column-padded 537->640 with zeros) ----------
__global__ __launch_bounds__(256) void convw_all(const float* __restrict__ w_in, const float* __restrict__ w_emb,
                                                 const float* __restrict__ w_out,
                                                 ushort* __restrict__ o1, ushort* __restrict__ o2, ushort* __restrict__ o3) {
    int i = blockIdx.x * 256 + threadIdx.x;
    if (i < 524288) {                                  // 512x1024
        o1[i] = f2bf(w_in[i]);
    } else if (i < 524288 + 327680) {                  // 512x640 padded
        int j = i - 524288;
        int r = j / 640, c = j - r * 640;
        o2[j] = (c < 537) ? f2bf(w_emb[(size_t)r * 537 + c]) : (ushort)0;
    } else if (i < 524288 + 327680 + 262144) {         // 512x512
        int j = i - 851968;
        o3[j] = f2bf(w_out[j]);
    }
}

// ---------- 256x256 GEMM, BK=32, 4-deep counted-vmcnt pipeline (T3/T4), fused stats ----------
// C[m][o] = sum_k A[m][k] * Bw[o][k].  8 waves (2M x 4N), per-wave C = 128x64.
// LDS: 4 buffers x (A 16KB + B 16KB) = 128 KiB.  Per tile/wave: 4 global_load_lds,
// 12 ds_read_b128, 32 MFMA.  Main-loop wait is vmcnt(8): tiles t+2,t+3 stay in
// flight across the raw barrier (~950 cy prefetch depth); never drains to 0.
// Invariants: STAGE(t+3) writes buf[(t+3)&3] whose readers (tile t-1) finished at
// barrier t-1; barrier t follows vmcnt(8) in every wave => tile t+1 fully landed
// before any wave reads it.  BK=32 rows are 64B so the 16-row x 4-slot fragment
// reads cover each 1KB block exactly once => bank-uniform, no swizzle needed.
__global__ __launch_bounds__(512, 2) void gemm256(const ushort* __restrict__ A, const ushort* __restrict__ Bw,
                                                  ushort* __restrict__ C, int K, int ldC,
                                                  float* __restrict__ st) {
    __shared__ ushort Asm[4][256][32];
    __shared__ ushort Bsm[4][256][32];

    int id = blockIdx.x;                       // 512 blocks
    int swz = (id & 7) * 64 + (id >> 3);       // XCD x owns swz [x*64, x*64+64)
    int row0 = (swz >> 1) * 256, col0 = (swz & 1) * 256;

    int t = threadIdx.x, wv = t >> 6, lane = t & 63;
    int wr = wv >> 2, wc = wv & 3;             // wave grid 2M x 4N
    int g = lane >> 4, rr = lane & 15;

    // staging: wave wv, chunk j covers rows [wv*16+128j, +16); lane l writes
    // LDS base + l*16 <- global row (wv*16 + (l>>2) + 128j), k-offset 8*(l&3)
    int srow = wv * 16 + (lane >> 2);
    int skoff = 8 * (lane & 3);
    const ushort* pa0 = A + (size_t)(row0 + srow) * K + skoff;
    const ushort* pa1 = A + (size_t)(row0 + srow + 128) * K + skoff;
    const ushort* pb0 = Bw + (size_t)(col0 + srow) * K + skoff;
    const ushort* pb1 = Bw + (size_t)(col0 + srow + 128) * K + skoff;

    const f32x4 fz = {0.f, 0.f, 0.f, 0.f};
    f32x4 acc[8][4];
#pragma unroll
    for (int i = 0; i < 8; ++i)
#pragma unroll
        for (int j = 0; j < 4; ++j) acc[i][j] = fz;

    int NT = K >> 5;                            // 32 / 20 / 16  (all >= 4)

#define STAGE(dbuf, kt) do { int k0_ = (kt) * 32;                                 \
        async16(pa0 + k0_, &Asm[dbuf][wv * 16][0]);                               \
        async16(pa1 + k0_, &Asm[dbuf][wv * 16 + 128][0]);                         \
        async16(pb0 + k0_, &Bsm[dbuf][wv * 16][0]);                               \
        async16(pb1 + k0_, &Bsm[dbuf][wv * 16 + 128][0]);                         \
    } while (0)

#define COMPUTE(cb) do {                                                          \
        s16x8 av[8], bv[4];                                                       \
        _Pragma("unroll") for (int mi = 0; mi < 8; ++mi)                          \
            av[mi] = *(const s16x8*)&Asm[cb][wr * 128 + mi * 16 + rr][g * 8];     \
        _Pragma("unroll") for (int ni = 0; ni < 4; ++ni)                          \
            bv[ni] = *(const s16x8*)&Bsm[cb][wc * 64 + ni * 16 + rr][g * 8];      \
        __builtin_amdgcn_s_setprio(1);                                            \
        _Pragma("unroll") for (int mi = 0; mi < 8; ++mi)                          \
            _Pragma("unroll") for (int ni = 0; ni < 4; ++ni)                      \
                acc[mi][ni] = __builtin_amdgcn_mfma_f32_16x16x32_bf16(            \
                    av[mi], bv[ni], acc[mi][ni], 0, 0, 0);                        \
        __builtin_amdgcn_s_setprio(0);                                            \
    } while (0)

    // prologue: 3 tiles in flight, require tile 0 landed (12 -> 8 outstanding)
    STAGE(0, 0); STAGE(1, 1); STAGE(2, 2);
    asm volatile("s_waitcnt vmcnt(8)" ::: "memory");
    __builtin_amdgcn_s_barrier();

    for (int kt = 0; kt < NT - 3; ++kt) {
        STAGE((kt + 3) & 3, kt + 3);
        COMPUTE(kt & 3);
        asm volatile("s_waitcnt vmcnt(8)" ::: "memory");   // tile kt+1 landed; kt+2,kt+3 in flight
        __builtin_amdgcn_s_barrier();
    }
    // epilogue: tiles NT-3..NT-1 already staged; drain 8 -> 4 -> 0
    COMPUTE((NT - 3) & 3);
    asm volatile("s_waitcnt vmcnt(4)" ::: "memory");
    __builtin_amdgcn_s_barrier();
    COMPUTE((NT - 2) & 3);
    asm volatile("s_waitcnt vmcnt(0)" ::: "memory");
    __builtin_amdgcn_s_barrier();
    COMPUTE((NT - 1) & 3);
#undef STAGE
#undef COMPUTE

    // epilogue: C write (C/D layout: col = lane&15, row = (lane>>4)*4 + reg) + fused stats
#pragma unroll
    for (int mi = 0; mi < 8; ++mi)
#pragma unroll
        for (int ni = 0; ni < 4; ++ni)
#pragma unroll
            for (int e2 = 0; e2 < 4; ++e2) {
                int row = row0 + wr * 128 + mi * 16 + g * 4 + e2;
                int col = col0 + wc * 64 + ni * 16 + rr;
                C[(size_t)row * ldC + col] = f2bf(acc[mi][ni][e2]);
            }
#pragma unroll
    for (int ni = 0; ni < 4; ++ni) {
        float s = 0.f, q = 0.f;
#pragma unroll
        for (int mi = 0; mi < 8; ++mi)
#pragma unroll
            for (int e2 = 0; e2 < 4; ++e2) {
                float v = acc[mi][ni][e2];
                s += v; q += v * v;
            }
        s += __shfl_xor(s, 16); s += __shfl_xor(s, 32);
        q += __shfl_xor(q, 16); q += __shfl_xor(q, 32);
        if (lane < 16) {
            int col = col0 + wc * 64 + ni * 16 + rr;
            atomicAdd(st + col, s);
            atomicAdd(st + 512 + col, q);
        }
    }
}

// ---------- LDS-tiled selfcorr: BN1+ReLU fused into staging, 4x4 patch + 8x8 halo ----------
#define RSTEP(S, HALF)                                                            \
    _Pragma("unroll") for (int i_ = 0; i_ < HALF; ++i_) {                         \
        float lo_ = p[i_], hi_ = p[HALF + i_];                                    \
        float send_ = (lane & S) ? lo_ : hi_;                                     \
        float keep_ = (lane & S) ? hi_ : lo_;                                     \
        p[i_] = keep_ + __shfl_xor(send_, S);                                     \
    }

__global__ __launch_bounds__(256) void selfcorr2(const ushort* __restrict__ y1, ushort* __restrict__ feat,
                                                 const float* __restrict__ st,
                                                 const float* __restrict__ gamma, const float* __restrict__ beta) {
    __shared__ ushort hl[64 * 512];        // 8x8 halo rows x 512 ch, post-BN bf16
    int h = blockIdx.x;                    // 4096 blocks; XCD swizzle for halo L2 reuse
    int xcd = h & 7, slot = h >> 3;
    int flat = xcd * 512 + slot;
    int bz = flat >> 8, rem = flat & 255;
    int y0 = (rem >> 4) * 4, x0 = (rem & 15) * 4;

    int t = threadIdx.x, wv = t >> 6, lane = t & 63;

    float scv[8], shv[8];
#pragma unroll
    for (int i = 0; i < 8; ++i) {
        int c = lane * 8 + i;
        float mean = st[c] * (1.f / 65536.f);
        float var = st[512 + c] * (1.f / 65536.f) - mean * mean;
        float rs = rsqrtf(var + 1e-5f);
        float s = rs * gamma[c];
        scv[i] = s; shv[i] = beta[c] - mean * s;
    }

#pragma unroll
    for (int i = 0; i < 16; ++i) {
        int rid = i * 4 + wv;              // wave reads one contiguous 1KB row
        int ry = rid >> 3, rx = rid & 7;
        int y = y0 - 2 + ry, x = x0 - 2 + rx;
        uint4 w4 = {0u, 0u, 0u, 0u};
        if (y >= 0 && y < 64 && x >= 0 && x < 64) {
            int n2 = (bz << 12) + (y << 6) + x;
            uint4 v = *(const uint4*)(y1 + (size_t)n2 * 512 + lane * 8);
            float a0 = fmaxf(bf2f(v.x & 0xffffu) * scv[0] + shv[0], 0.f);
            float a1 = fmaxf(bf2f(v.x >> 16)     * scv[1] + shv[1], 0.f);
            float a2 = fmaxf(bf2f(v.y & 0xffffu) * scv[2] + shv[2], 0.f);
            float a3 = fmaxf(bf2f(v.y >> 16)     * scv[3] + shv[3], 0.f);
            float a4 = fmaxf(bf2f(v.z & 0xffffu) * scv[4] + shv[4], 0.f);
            float a5 = fmaxf(bf2f(v.z >> 16)     * scv[5] + shv[5], 0.f);
            float a6 = fmaxf(bf2f(v.w & 0xffffu) * scv[6] + shv[6], 0.f);
            float a7 = fmaxf(bf2f(v.w >> 16)     * scv[7] + shv[7], 0.f);
            w4.x = (uint)f2bf(a0) | ((uint)f2bf(a1) << 16);
            w4.y = (uint)f2bf(a2) | ((uint)f2bf(a3) << 16);
            w4.z = (uint)f2bf(a4) | ((uint)f2bf(a5) << 16);
            w4.w = (uint)f2bf(a6) | ((uint)f2bf(a7) << 16);
        }
        *(uint4*)&hl[rid * 512 + lane * 8] = w4;
    }
    __syncthreads();

    // write back normalized interior h1
#pragma unroll
    for (int i = 0; i < 4; ++i) {
        int pid = i * 4 + wv;
        int py = pid >> 2, px = pid & 3;
        int rid = (py + 2) * 8 + (px + 2);
        uint4 v = *(const uint4*)&hl[rid * 512 + lane * 8];
        int n2 = (bz << 12) + ((y0 + py) << 6) + (x0 + px);
        *(uint4*)(feat + (size_t)n2 * LDF + lane * 8) = v;
    }

    for (int j = 0; j < 4; ++j) {
        int crid = (wv + 2) * 8 + (j + 2);
        uint4 cv = *(const uint4*)&hl[crid * 512 + lane * 8];
        float cf[8];
        cf[0] = bf2f(cv.x & 0xffffu); cf[1] = bf2f(cv.x >> 16);
        cf[2] = bf2f(cv.y & 0xffffu); cf[3] = bf2f(cv.y >> 16);
        cf[4] = bf2f(cv.z & 0xffffu); cf[5] = bf2f(cv.z >> 16);
        cf[6] = bf2f(cv.w & 0xffffu); cf[7] = bf2f(cv.w >> 16);

        float p[32];
#pragma unroll
        for (int i = 0; i < 32; ++i) p[i] = 0.f;
#pragma unroll
        for (int tap = 0; tap < 25; ++tap) {
            int dy = tap / 5 - 2, dx = tap % 5 - 2;
            int rid = (wv + 2 + dy) * 8 + (j + 2 + dx);
            uint4 nv = *(const uint4*)&hl[rid * 512 + lane * 8];
            p[tap] = cf[0] * bf2f(nv.x & 0xffffu) + cf[1] * bf2f(nv.x >> 16)
                   + cf[2] * bf2f(nv.y & 0xffffu) + cf[3] * bf2f(nv.y >> 16)
                   + cf[4] * bf2f(nv.z & 0xffffu) + cf[5] * bf2f(nv.z >> 16)
                   + cf[6] * bf2f(nv.w & 0xffffu) + cf[7] * bf2f(nv.w >> 16);
        }
        RSTEP(1, 16) RSTEP(2, 8) RSTEP(4, 4) RSTEP(8, 2) RSTEP(16, 1)
        float d = p[0] + __shfl_xor(p[0], 32);
        float v2 = d * d;
#pragma unroll
        for (int m = 1; m < 64; m <<= 1) v2 += __shfl_xor(v2, m);   // = 2 * sum_t dot^2
        float inv = rsqrtf(0.5f * v2 + 1e-6f);
        int tt = ((lane & 1) << 4) | ((lane & 2) << 2) | (lane & 4) | ((lane & 8) >> 2) | ((lane & 16) >> 4);
        if (lane < 32 && tt < 25) {
            int n2 = (bz << 12) + ((y0 + wv) << 6) + (x0 + j);
            feat[(size_t)n2 * LDF + 512 + tt] = f2bf(d * inv);
        }
    }
}

// ---------- in-place BN+ReLU on [n][512] bf16 ----------
__global__ __launch_bounds__(256) void apply_bn(ushort* __restrict__ Y, int ld, const float* __restrict__ st,
                                                const float* __restrict__ gamma, const float* __restrict__ beta,
                                                int relu) {
    __shared__ float sc[512], sh[512];
    int t = threadIdx.x;
    for (int c = t; c < 512; c += 256) {
        float mean = st[c] * (1.f / 65536.f);
        float var = st[512 + c] * (1.f / 65536.f) - mean * mean;
        float rs = rsqrtf(var + 1e-5f);
        float s = rs * gamma[c];
        sc[c] = s; sh[c] = beta[c] - mean * s;
    }
    __syncthreads();
    float s0 = sc[t * 2], s1 = sc[t * 2 + 1], h0 = sh[t * 2], h1v = sh[t * 2 + 1];
    for (int row = blockIdx.x; row < NPIX; row += gridDim.x) {
        uint* p = (uint*)(Y + (size_t)row * ld + t * 2);
        uint v = *p;
        float a = bf2f(v & 0xffffu) * s0 + h0;
        float b = bf2f(v >> 16) * s1 + h1v;
        if (relu) { a = fmaxf(a, 0.f); b = fmaxf(b, 0.f); }
        *p = (uint)f2bf(a) | ((uint)f2bf(b) << 16);
    }
}

// ---------- final: BN (no ReLU) + transpose [n][o] -> (b,o,h,w) fp32 ----------
__global__ __launch_bounds__(256) void finalk(const ushort* __restrict__ y3, const float* __restrict__ st,
                                              const float* __restrict__ gamma, const float* __restrict__ beta,
                                              float* __restrict__ out) {
    __shared__ float tile[32][33];
    int t = threadIdx.x, col = t & 31, rq = t >> 5;
    int n0 = blockIdx.x * 32, o0 = blockIdx.y * 32;
#pragma unroll
    for (int r = 0; r < 4; ++r) {
        int row = rq + r * 8;                        // n_local
        tile[row][col] = bf2f((uint)y3[(size_t)(n0 + row) * 512 + o0 + col]);
    }
    __syncthreads();
    int b = n0 >> 12, s0 = n0 & 4095;
#pragma unroll
    for (int r = 0; r < 4; ++r) {
        int orow = rq + r * 8;                       // o_local
        int o = o0 + orow;
        float mean = st[o] * (1.f / 65536.f);
        float var = st[512 + o] * (1.f / 65536.f) - mean * mean;
        float rs = rsqrtf(var + 1e-5f);
        float sc = rs * gamma[o];
        float sh = beta[o] - mean * sc;
        out[((size_t)b * 512 + o) * 4096 + s0 + col] = tile[col][orow] * sc + sh;
    }
}

// ---------- launch ----------
extern "C" void kernel_launch(void* const* d_in, const int* in_sizes, int n_in,
                              void* d_out, int out_size, void* d_ws, size_t ws_size,
                              hipStream_t stream) {
    (void)in_sizes; (void)n_in; (void)out_size; (void)ws_size;
    const float* x     = (const float*)d_in[0];
    const float* w_in  = (const float*)d_in[1];
    const float* g1    = (const float*)d_in[2];
    const float* b1    = (const float*)d_in[3];
    const float* w_emb = (const float*)d_in[4];
    const float* g2    = (const float*)d_in[5];
    const float* b2    = (const float*)d_in[6];
    const float* w_out = (const float*)d_in[7];
    const float* g3    = (const float*)d_in[8];
    const float* b3    = (const float*)d_in[9];
    float* out = (float*)d_out;

    char* ws = (char*)d_ws;
    // layout (bytes):
    //   [0, 128Mi)           xT [65536][1024] bf16; reused as h2 [65536][512] after GEMM2
    //   [128Mi, 192Mi)       y1 raw [65536][512] bf16; reused as y3
    //   [192Mi, 192Mi+80Mi)  feat [65536][640] bf16 (h1' | gs | zero-weight pad)
    //   then bf16 weights + 3x1024 f32 stats
    ushort* xT   = (ushort*)ws;
    ushort* h2   = (ushort*)ws;
    ushort* y1   = (ushort*)(ws + 134217728);
    ushort* y3   = (ushort*)(ws + 134217728);
    ushort* feat = (ushort*)(ws + 201326592);
    char* wb     = ws + 201326592 + 83886080;
    ushort* wbin  = (ushort*)wb;                             // 512*1024*2 = 1048576
    ushort* wbemb = (ushort*)(wb + 1048576);                 // 512*640*2  = 655360
    ushort* wbout = (ushort*)(wb + 1048576 + 655360);        // 512*512*2  = 524288
    float*  stats = (float*)(wb + 1048576 + 655360 + 524288);// 3*1024 f32

    hipMemsetAsync(stats, 0, 3 * 1024 * sizeof(float), stream);
    convw_all<<<4352, 256, 0, stream>>>(w_in, w_emb, w_out, wbin, wbemb, wbout);
    txpose<<<dim3(128, 32, 16), 256, 0, stream>>>(x, xT);

    // stage 1: conv1x1_in (raw) + fused stats
    gemm256<<<512, 512, 0, stream>>>(xT, wbin, y1, 1024, 512, stats);
    // BN1+ReLU fused into selfcorr staging; writes h1' and gs into feat
    selfcorr2<<<4096, 256, 0, stream>>>(y1, feat, stats, g1, b1);

    // stage 2: embeddingFea + fused stats, then BN+ReLU in place
    gemm256<<<512, 512, 0, stream>>>(feat, wbemb, h2, 640, 512, stats + 1024);
    apply_bn<<<2048, 256, 0, stream>>>(h2, 512, stats + 1024, g2, b2, 1);

    // stage 3: conv1x1_out + fused stats, then BN + transpose to NCHW
    gemm256<<<512, 512, 0, stream>>>(h2, wbout, y3, 512, 512, stats + 2048);
    finalk<<<dim3(2048, 16), 256, 0, stream>>>(y3, stats + 2048, g3, b3, out);
}

// Round 5
// 478.309 us; speedup vs baseline: 1.1001x; 1.1001x over previous
//
#include <hip/hip_runtime.h>

typedef unsigned int uint;
typedef unsigned short ushort;

using s16x8 = __attribute__((ext_vector_type(8))) short;
using f32x4 = __attribute__((ext_vector_type(4))) float;

#define NPIX 65536   // 16 * 64 * 64 pixels

// ---------- helpers ----------
__device__ __forceinline__ ushort f2bf(float f) {
    uint u = __float_as_uint(f);
    u += 0x7fffu + ((u >> 16) & 1u);   // RNE
    return (ushort)(u >> 16);
}
__device__ __forceinline__ float bf2f(uint h) { return __uint_as_float(h << 16); }

__device__ __forceinline__ void async16(const void* g, void* l) {
    __builtin_amdgcn_global_load_lds(
        (const __attribute__((address_space(1))) void*)g,
        (__attribute__((address_space(3))) void*)l, 16, 0, 0);
}

// ---------- prep: txpose (x NCHW fp32 -> xT [n][c] bf16) + weight cvt + stats zero ----------
__global__ __launch_bounds__(256) void prep(const float* __restrict__ x, const float* __restrict__ w_in,
                                            const float* __restrict__ w_emb, const float* __restrict__ w_out,
                                            ushort* __restrict__ xT, ushort* __restrict__ o1,
                                            ushort* __restrict__ o2, ushort* __restrict__ o3,
                                            float* __restrict__ stats) {
    int id = blockIdx.x, t = threadIdx.x;
    if (id < 65536) {                                  // txpose: 128 x 32 x 16
        __shared__ float tile[32][33];
        int bx = id & 127, by = (id >> 7) & 31, bz = id >> 12;
        int col = t & 31, rq = t >> 5;
        size_t srcBase = ((size_t)bz * 1024 + by * 32) * 4096 + bx * 32;
#pragma unroll
        for (int r = 0; r < 4; ++r) {
            int row = rq + r * 8;                       // c_local
            tile[row][col] = x[srcBase + (size_t)row * 4096 + col];
        }
        __syncthreads();
        size_t dstBase = ((size_t)bz * 4096 + bx * 32) * 1024 + by * 32;
#pragma unroll
        for (int r = 0; r < 4; ++r) {
            int row = rq + r * 8;                       // s_local
            xT[dstBase + (size_t)row * 1024 + col] = f2bf(tile[col][row]);
        }
    } else if (id < 65536 + 4352) {                    // weight convert
        int i = (id - 65536) * 256 + t;
        if (i < 524288) {                              // w_in 512x1024
            o1[i] = f2bf(w_in[i]);
        } else if (i < 524288 + 327680) {              // w_emb 512x640 (537 real, pad 0)
            int j = i - 524288;
            int r = j / 640, c = j - r * 640;
            o2[j] = (c < 537) ? f2bf(w_emb[(size_t)r * 537 + c]) : (ushort)0;
        } else {                                       // w_out 512x512
            int j = i - 851968;
            o3[j] = f2bf(w_out[j]);
        }
    } else {                                           // stats zero: 3*1024 floats
#pragma unroll
        for (int r = 0; r < 12; ++r) stats[r * 256 + t] = 0.f;
    }
}

// ---------- GEMM1: 256x256 BK=64 2-phase, T2 swizzle, async staging, fused stats (R3 engine) ----------
__global__ __launch_bounds__(512, 2) void gemm256(const ushort* __restrict__ A, const ushort* __restrict__ Bw,
                                                  ushort* __restrict__ C, int K, int ldC,
                                                  float* __restrict__ st) {
    __shared__ ushort Asm[2][256][64];
    __shared__ ushort Bsm[2][256][64];

    int id = blockIdx.x;                       // 512 blocks
    int swz = (id & 7) * 64 + (id >> 3);       // XCD x owns swz [x*64, x*64+64)
    int row0 = (swz >> 1) * 256, col0 = (swz & 1) * 256;

    int t = threadIdx.x, wv = t >> 6, lane = t & 63;
    int wr = wv >> 2, wc = wv & 3;             // wave grid 2M x 4N
    int g = lane >> 4, rr = lane & 15;

    int srow = t >> 3;
    int scol = ((t & 7) * 16) ^ ((srow & 7) << 4);     // pre-swizzled logical col byte
    const ushort* pa = A + (size_t)(row0 + srow) * K + (scol >> 1);
    const ushort* pb = Bw + (size_t)(col0 + srow) * K + (scol >> 1);

    const f32x4 fz = {0.f, 0.f, 0.f, 0.f};
    f32x4 acc[8][4];
#pragma unroll
    for (int i = 0; i < 8; ++i)
#pragma unroll
        for (int j = 0; j < 4; ++j) acc[i][j] = fz;

    int NT = K >> 6;

#define STAGE(dbuf, kt) do {                                                      \
        int k0_ = (kt) * 64;                                                      \
        _Pragma("unroll") for (int q_ = 0; q_ < 4; ++q_) {                        \
            async16(pa + (size_t)q_ * 64 * K + k0_, &Asm[dbuf][q_ * 64 + wv * 8][0]); \
            async16(pb + (size_t)q_ * 64 * K + k0_, &Bsm[dbuf][q_ * 64 + wv * 8][0]); \
        }                                                                         \
    } while (0)

    STAGE(0, 0);
    __syncthreads();

    int swzl = (rr & 7) << 4;
    for (int kt = 0; kt < NT; ++kt) {
        int c = kt & 1;
        if (kt + 1 < NT) STAGE(c ^ 1, kt + 1);

        s16x8 bfr[4][2];
#pragma unroll
        for (int ni = 0; ni < 4; ++ni)
#pragma unroll
            for (int ks = 0; ks < 2; ++ks)
                bfr[ni][ks] = *(const s16x8*)&Bsm[c][wc * 64 + ni * 16 + rr][((ks * 64 + g * 16) ^ swzl) >> 1];

#pragma unroll
        for (int pp = 0; pp < 4; ++pp) {
            s16x8 afr[2][2];
#pragma unroll
            for (int m2 = 0; m2 < 2; ++m2)
#pragma unroll
                for (int ks = 0; ks < 2; ++ks)
                    afr[m2][ks] = *(const s16x8*)&Asm[c][wr * 128 + (pp * 2 + m2) * 16 + rr][((ks * 64 + g * 16) ^ swzl) >> 1];
            __builtin_amdgcn_s_setprio(1);
#pragma unroll
            for (int m2 = 0; m2 < 2; ++m2)
#pragma unroll
                for (int ni = 0; ni < 4; ++ni)
#pragma unroll
                    for (int ks = 0; ks < 2; ++ks)
                        acc[pp * 2 + m2][ni] = __builtin_amdgcn_mfma_f32_16x16x32_bf16(
                            afr[m2][ks], bfr[ni][ks], acc[pp * 2 + m2][ni], 0, 0, 0);
            __builtin_amdgcn_s_setprio(0);
        }
        __syncthreads();
    }
#undef STAGE

#pragma unroll
    for (int mi = 0; mi < 8; ++mi)
#pragma unroll
        for (int ni = 0; ni < 4; ++ni)
#pragma unroll
            for (int e2 = 0; e2 < 4; ++e2) {
                int row = row0 + wr * 128 + mi * 16 + g * 4 + e2;
                int col = col0 + wc * 64 + ni * 16 + rr;
                C[(size_t)row * ldC + col] = f2bf(acc[mi][ni][e2]);
            }
#pragma unroll
    for (int ni = 0; ni < 4; ++ni) {
        float s = 0.f, q = 0.f;
#pragma unroll
        for (int mi = 0; mi < 8; ++mi)
#pragma unroll
            for (int e2 = 0; e2 < 4; ++e2) {
                float v = acc[mi][ni][e2];
                s += v; q += v * v;
            }
        s += __shfl_xor(s, 16); s += __shfl_xor(s, 32);
        q += __shfl_xor(q, 16); q += __shfl_xor(q, 32);
        if (lane < 16) {
            int col = col0 + wc * 64 + ni * 16 + rr;
            atomicAdd(st + col, s);
            atomicAdd(st + 512 + col, q);
        }
    }
}

// ---------- GEMM2/3: reg-staged A with fused BN+ReLU (T14 split); gs tiles via async ----------
// A-tile kt<8: raw Araw [n][512] + BN(stin,gamma,beta)+ReLU, reg-staged with swizzled ds_write.
// A-tile kt>=8 (GEMM2 only): gs [n][128] via global_load_lds with pre-swizzled source.
// B always async from Bw [512][Kb]. Output raw C + fused stats.
__global__ __launch_bounds__(512, 2) void gemm_reg(const ushort* __restrict__ Araw, const ushort* __restrict__ gsrc,
                                                   const ushort* __restrict__ Bw, ushort* __restrict__ C,
                                                   int Kb, int NT,
                                                   const float* __restrict__ stin, const float* __restrict__ gamma,
                                                   const float* __restrict__ beta, float* __restrict__ stout) {
    __shared__ ushort Asm[2][256][64];
    __shared__ ushort Bsm[2][256][64];

    int id = blockIdx.x;
    int swz = (id & 7) * 64 + (id >> 3);
    int row0 = (swz >> 1) * 256, col0 = (swz & 1) * 256;

    int t = threadIdx.x, wv = t >> 6, lane = t & 63;
    int wr = wv >> 2, wc = wv & 3;
    int g = lane >> 4, rr = lane & 15;

    int srow = t >> 3;
    int kb = (t & 7) * 16;                         // logical col byte (k-bytes within 128B row)
    int scol = kb ^ ((srow & 7) << 4);             // pre-swizzled (for async paths)
    const ushort* pb = Bw + (size_t)(col0 + srow) * Kb + (scol >> 1);
    const ushort* pg = gsrc + (size_t)(row0 + srow) * 128 + (scol >> 1);
    int wofs = (kb ^ ((srow & 7) << 4)) >> 1;      // swizzled LDS elem offset for reg writes

    const f32x4 fz = {0.f, 0.f, 0.f, 0.f};
    f32x4 acc[8][4];
#pragma unroll
    for (int i = 0; i < 8; ++i)
#pragma unroll
        for (int j = 0; j < 4; ++j) acc[i][j] = fz;

    uint4 rq0, rq1, rq2, rq3;
    float scq[8], shq[8];

#define BSTAGE(dbuf, kt) do { int k0_ = (kt) * 64;                                \
        _Pragma("unroll") for (int q_ = 0; q_ < 4; ++q_)                          \
            async16(pb + (size_t)q_ * 64 * Kb + k0_, &Bsm[dbuf][q_ * 64 + wv * 8][0]); \
    } while (0)

#define GSTAGE(dbuf, kt) do { int k0_ = (kt) * 64 - 512;                          \
        _Pragma("unroll") for (int q_ = 0; q_ < 4; ++q_)                          \
            async16(pg + (size_t)q_ * 64 * 128 + k0_, &Asm[dbuf][q_ * 64 + wv * 8][0]); \
    } while (0)

#define LOADQ(kt) do { int c0_ = (kt) * 64 + (t & 7) * 8;                         \
        float4 m1_ = *(const float4*)&stin[c0_], m2_ = *(const float4*)&stin[c0_ + 4]; \
        float4 v1_ = *(const float4*)&stin[512 + c0_], v2_ = *(const float4*)&stin[512 + c0_ + 4]; \
        float4 g1_ = *(const float4*)&gamma[c0_], g2_ = *(const float4*)&gamma[c0_ + 4]; \
        float4 b1_ = *(const float4*)&beta[c0_],  b2_ = *(const float4*)&beta[c0_ + 4]; \
        float mm_[8] = {m1_.x, m1_.y, m1_.z, m1_.w, m2_.x, m2_.y, m2_.z, m2_.w};  \
        float vv_[8] = {v1_.x, v1_.y, v1_.z, v1_.w, v2_.x, v2_.y, v2_.z, v2_.w};  \
        float gg_[8] = {g1_.x, g1_.y, g1_.z, g1_.w, g2_.x, g2_.y, g2_.z, g2_.w};  \
        float bb_[8] = {b1_.x, b1_.y, b1_.z, b1_.w, b2_.x, b2_.y, b2_.z, b2_.w};  \
        _Pragma("unroll") for (int j_ = 0; j_ < 8; ++j_) {                        \
            float mean_ = mm_[j_] * (1.f / 65536.f);                              \
            float var_ = vv_[j_] * (1.f / 65536.f) - mean_ * mean_;               \
            float s_ = rsqrtf(var_ + 1e-5f) * gg_[j_];                            \
            scq[j_] = s_; shq[j_] = bb_[j_] - mean_ * s_;                         \
        }                                                                         \
        const ushort* pa_ = Araw + (size_t)(row0 + srow) * 512 + c0_;             \
        rq0 = *(const uint4*)(pa_);                                               \
        rq1 = *(const uint4*)(pa_ + 64 * 512);                                    \
        rq2 = *(const uint4*)(pa_ + 128 * 512);                                   \
        rq3 = *(const uint4*)(pa_ + 192 * 512);                                   \
    } while (0)

#define XFORM1(rv) do {                                                           \
        uint w_[4]; uint in_[4] = {rv.x, rv.y, rv.z, rv.w};                       \
        _Pragma("unroll") for (int p_ = 0; p_ < 4; ++p_) {                        \
            float a_ = fmaxf(bf2f(in_[p_] & 0xffffu) * scq[p_ * 2] + shq[p_ * 2], 0.f); \
            float b_ = fmaxf(bf2f(in_[p_] >> 16) * scq[p_ * 2 + 1] + shq[p_ * 2 + 1], 0.f); \
            w_[p_] = (uint)f2bf(a_) | ((uint)f2bf(b_) << 16);                     \
        }                                                                         \
        rv.x = w_[0]; rv.y = w_[1]; rv.z = w_[2]; rv.w = w_[3];                   \
    } while (0)

#define WRITEQ(dbuf) do {                                                         \
        XFORM1(rq0); XFORM1(rq1); XFORM1(rq2); XFORM1(rq3);                       \
        *(uint4*)&Asm[dbuf][srow][wofs]       = rq0;                              \
        *(uint4*)&Asm[dbuf][srow + 64][wofs]  = rq1;                              \
        *(uint4*)&Asm[dbuf][srow + 128][wofs] = rq2;                              \
        *(uint4*)&Asm[dbuf][srow + 192][wofs] = rq3;                              \
    } while (0)

#define COMPUTE(cb) do {                                                          \
        s16x8 bfr[4][2];                                                          \
        _Pragma("unroll") for (int ni = 0; ni < 4; ++ni)                          \
            _Pragma("unroll") for (int ks = 0; ks < 2; ++ks)                      \
                bfr[ni][ks] = *(const s16x8*)&Bsm[cb][wc * 64 + ni * 16 + rr][((ks * 64 + g * 16) ^ swzl) >> 1]; \
        _Pragma("unroll") for (int pp = 0; pp < 4; ++pp) {                        \
            s16x8 afr[2][2];                                                      \
            _Pragma("unroll") for (int m2 = 0; m2 < 2; ++m2)                      \
                _Pragma("unroll") for (int ks = 0; ks < 2; ++ks)                  \
                    afr[m2][ks] = *(const s16x8*)&Asm[cb][wr * 128 + (pp * 2 + m2) * 16 + rr][((ks * 64 + g * 16) ^ swzl) >> 1]; \
            __builtin_amdgcn_s_setprio(1);                                        \
            _Pragma("unroll") for (int m2 = 0; m2 < 2; ++m2)                      \
                _Pragma("unroll") for (int ni = 0; ni < 4; ++ni)                  \
                    _Pragma("unroll") for (int ks = 0; ks < 2; ++ks)              \
                        acc[pp * 2 + m2][ni] = __builtin_amdgcn_mfma_f32_16x16x32_bf16( \
                            afr[m2][ks], bfr[ni][ks], acc[pp * 2 + m2][ni], 0, 0, 0); \
            __builtin_amdgcn_s_setprio(0);                                        \
        }                                                                         \
    } while (0)

    int swzl = (rr & 7) << 4;

    // prologue: tile 0 (always a reg tile: NT >= 8)
    BSTAGE(0, 0);
    LOADQ(0);
    WRITEQ(0);
    __syncthreads();

    for (int kt = 0; kt < NT; ++kt) {
        int c = kt & 1;
        int next = kt + 1;
        if (next < NT) {
            BSTAGE(c ^ 1, next);
            if (next < 8) LOADQ(next); else GSTAGE(c ^ 1, next);
        }
        COMPUTE(c);
        if (next < NT && next < 8) WRITEQ(c ^ 1);
        __syncthreads();
    }
#undef BSTAGE
#undef GSTAGE
#undef LOADQ
#undef XFORM1
#undef WRITEQ
#undef COMPUTE

#pragma unroll
    for (int mi = 0; mi < 8; ++mi)
#pragma unroll
        for (int ni = 0; ni < 4; ++ni)
#pragma unroll
            for (int e2 = 0; e2 < 4; ++e2) {
                int row = row0 + wr * 128 + mi * 16 + g * 4 + e2;
                int col = col0 + wc * 64 + ni * 16 + rr;
                C[(size_t)row * 512 + col] = f2bf(acc[mi][ni][e2]);
            }
#pragma unroll
    for (int ni = 0; ni < 4; ++ni) {
        float s = 0.f, q = 0.f;
#pragma unroll
        for (int mi = 0; mi < 8; ++mi)
#pragma unroll
            for (int e2 = 0; e2 < 4; ++e2) {
                float v = acc[mi][ni][e2];
                s += v; q += v * v;
            }
        s += __shfl_xor(s, 16); s += __shfl_xor(s, 32);
        q += __shfl_xor(q, 16); q += __shfl_xor(q, 32);
        if (lane < 16) {
            int col = col0 + wc * 64 + ni * 16 + rr;
            atomicAdd(stout + col, s);
            atomicAdd(stout + 512 + col, q);
        }
    }
}

// ---------- selfcorr: BN1+ReLU on staging, 4x4 patch + 8x8 halo, writes compact gs only ----------
#define RSTEP(S, HALF)                                                            \
    _Pragma("unroll") for (int i_ = 0; i_ < HALF; ++i_) {                         \
        float lo_ = p[i_], hi_ = p[HALF + i_];                                    \
        float send_ = (lane & S) ? lo_ : hi_;                                     \
        float keep_ = (lane & S) ? hi_ : lo_;                                     \
        p[i_] = keep_ + __shfl_xor(send_, S);                                     \
    }

__global__ __launch_bounds__(256) void selfcorr2(const ushort* __restrict__ y1, ushort* __restrict__ gs,
                                                 const float* __restrict__ st,
                                                 const float* __restrict__ gamma, const float* __restrict__ beta) {
    __shared__ ushort hl[64 * 512];        // 8x8 halo rows x 512 ch, post-BN bf16
    int h = blockIdx.x;                    // 4096 blocks; XCD swizzle for halo L2 reuse
    int xcd = h & 7, slot = h >> 3;
    int flat = xcd * 512 + slot;
    int bz = flat >> 8, rem = flat & 255;
    int y0 = (rem >> 4) * 4, x0 = (rem & 15) * 4;

    int t = threadIdx.x, wv = t >> 6, lane = t & 63;

    float scv[8], shv[8];
#pragma unroll
    for (int i = 0; i < 8; ++i) {
        int c = lane * 8 + i;
        float mean = st[c] * (1.f / 65536.f);
        float var = st[512 + c] * (1.f / 65536.f) - mean * mean;
        float rs = rsqrtf(var + 1e-5f);
        float s = rs * gamma[c];
        scv[i] = s; shv[i] = beta[c] - mean * s;
    }

#pragma unroll
    for (int i = 0; i < 16; ++i) {
        int rid = i * 4 + wv;              // wave reads one contiguous 1KB row
        int ry = rid >> 3, rx = rid & 7;
        int y = y0 - 2 + ry, x = x0 - 2 + rx;
        uint4 w4 = {0u, 0u, 0u, 0u};
        if (y >= 0 && y < 64 && x >= 0 && x < 64) {
            int n2 = (bz << 12) + (y << 6) + x;
            uint4 v = *(const uint4*)(y1 + (size_t)n2 * 512 + lane * 8);
            float a0 = fmaxf(bf2f(v.x & 0xffffu) * scv[0] + shv[0], 0.f);
            float a1 = fmaxf(bf2f(v.x >> 16)     * scv[1] + shv[1], 0.f);
            float a2 = fmaxf(bf2f(v.y & 0xffffu) * scv[2] + shv[2], 0.f);
            float a3 = fmaxf(bf2f(v.y >> 16)     * scv[3] + shv[3], 0.f);
            float a4 = fmaxf(bf2f(v.z & 0xffffu) * scv[4] + shv[4], 0.f);
            float a5 = fmaxf(bf2f(v.z >> 16)     * scv[5] + shv[5], 0.f);
            float a6 = fmaxf(bf2f(v.w & 0xffffu) * scv[6] + shv[6], 0.f);
            float a7 = fmaxf(bf2f(v.w >> 16)     * scv[7] + shv[7], 0.f);
            w4.x = (uint)f2bf(a0) | ((uint)f2bf(a1) << 16);
            w4.y = (uint)f2bf(a2) | ((uint)f2bf(a3) << 16);
            w4.z = (uint)f2bf(a4) | ((uint)f2bf(a5) << 16);
            w4.w = (uint)f2bf(a6) | ((uint)f2bf(a7) << 16);
        }
        *(uint4*)&hl[rid * 512 + lane * 8] = w4;
    }
    __syncthreads();

    for (int j = 0; j < 4; ++j) {
        int crid = (wv + 2) * 8 + (j + 2);
        uint4 cv = *(const uint4*)&hl[crid * 512 + lane * 8];
        float cf[8];
        cf[0] = bf2f(cv.x & 0xffffu); cf[1] = bf2f(cv.x >> 16);
        cf[2] = bf2f(cv.y & 0xffffu); cf[3] = bf2f(cv.y >> 16);
        cf[4] = bf2f(cv.z & 0xffffu); cf[5] = bf2f(cv.z >> 16);
        cf[6] = bf2f(cv.w & 0xffffu); cf[7] = bf2f(cv.w >> 16);

        float p[32];
#pragma unroll
        for (int i = 0; i < 32; ++i) p[i] = 0.f;
#pragma unroll
        for (int tap = 0; tap < 25; ++tap) {
            int dy = tap / 5 - 2, dx = tap % 5 - 2;
            int rid = (wv + 2 + dy) * 8 + (j + 2 + dx);
            uint4 nv = *(const uint4*)&hl[rid * 512 + lane * 8];
            p[tap] = cf[0] * bf2f(nv.x & 0xffffu) + cf[1] * bf2f(nv.x >> 16)
                   + cf[2] * bf2f(nv.y & 0xffffu) + cf[3] * bf2f(nv.y >> 16)
                   + cf[4] * bf2f(nv.z & 0xffffu) + cf[5] * bf2f(nv.z >> 16)
                   + cf[6] * bf2f(nv.w & 0xffffu) + cf[7] * bf2f(nv.w >> 16);
        }
        RSTEP(1, 16) RSTEP(2, 8) RSTEP(4, 4) RSTEP(8, 2) RSTEP(16, 1)
        float d = p[0] + __shfl_xor(p[0], 32);
        float v2 = d * d;
#pragma unroll
        for (int m = 1; m < 64; m <<= 1) v2 += __shfl_xor(v2, m);   // = 2 * sum_t dot^2
        float inv = rsqrtf(0.5f * v2 + 1e-6f);
        int tt = ((lane & 1) << 4) | ((lane & 2) << 2) | (lane & 4) | ((lane & 8) >> 2) | ((lane & 16) >> 4);
        if (lane < 32 && tt < 25) {
            int n2 = (bz << 12) + ((y0 + wv) << 6) + (x0 + j);
            gs[(size_t)n2 * 128 + tt] = f2bf(d * inv);
        }
    }
}

// ---------- final: BN3 (no ReLU) + transpose [n][o] -> (b,o,h,w) fp32 ----------
__global__ __launch_bounds__(256) void finalk(const ushort* __restrict__ y3, const float* __restrict__ st,
                                              const float* __restrict__ gamma, const float* __restrict__ beta,
                                              float* __restrict__ out) {
    __shared__ float tile[32][33];
    int t = threadIdx.x, col = t & 31, rq = t >> 5;
    int n0 = blockIdx.x * 32, o0 = blockIdx.y * 32;
#pragma unroll
    for (int r = 0; r < 4; ++r) {
        int row = rq + r * 8;                        // n_local
        tile[row][col] = bf2f((uint)y3[(size_t)(n0 + row) * 512 + o0 + col]);
    }
    __syncthreads();
    int b = n0 >> 12, s0 = n0 & 4095;
#pragma unroll
    for (int r = 0; r < 4; ++r) {
        int orow = rq + r * 8;                       // o_local
        int o = o0 + orow;
        float mean = st[o] * (1.f / 65536.f);
        float var = st[512 + o] * (1.f / 65536.f) - mean * mean;
        float rs = rsqrtf(var + 1e-5f);
        float sc = rs * gamma[o];
        float sh = beta[o] - mean * sc;
        out[((size_t)b * 512 + o) * 4096 + s0 + col] = tile[col][orow] * sc + sh;
    }
}

// ---------- launch ----------
extern "C" void kernel_launch(void* const* d_in, const int* in_sizes, int n_in,
                              void* d_out, int out_size, void* d_ws, size_t ws_size,
                              hipStream_t stream) {
    (void)in_sizes; (void)n_in; (void)out_size; (void)ws_size;
    const float* x     = (const float*)d_in[0];
    const float* w_in  = (const float*)d_in[1];
    const float* g1    = (const float*)d_in[2];
    const float* b1    = (const float*)d_in[3];
    const float* w_emb = (const float*)d_in[4];
    const float* g2    = (const float*)d_in[5];
    const float* b2    = (const float*)d_in[6];
    const float* w_out = (const float*)d_in[7];
    const float* g3    = (const float*)d_in[8];
    const float* b3    = (const float*)d_in[9];
    float* out = (float*)d_out;

    char* ws = (char*)d_ws;
    // layout (bytes):
    //   [0, 128Mi)       xT [65536][1024] bf16; dead after gemm1 -> h2 [65536][512] in [0,64Mi)
    //   [128Mi, 192Mi)   y1 raw [65536][512] bf16; dead after gemm2 -> y3 same region
    //   [192Mi, 208Mi)   gs [65536][128] bf16 (25 real cols; rest multiplied by zero weights)
    //   [208Mi, ...)     bf16 weights + 3x1024 f32 stats
    ushort* xT   = (ushort*)ws;
    ushort* h2   = (ushort*)ws;
    ushort* y1   = (ushort*)(ws + 134217728);
    ushort* y3   = (ushort*)(ws + 134217728);
    ushort* gs   = (ushort*)(ws + 201326592);
    char* wb     = ws + 201326592 + 16777216;
    ushort* wbin  = (ushort*)wb;                             // 512*1024*2 = 1048576
    ushort* wbemb = (ushort*)(wb + 1048576);                 // 512*640*2  = 655360
    ushort* wbout = (ushort*)(wb + 1048576 + 655360);        // 512*512*2  = 524288
    float*  stats = (float*)(wb + 1048576 + 655360 + 524288);// 3*1024 f32

    // prep: txpose (65536 blocks) + weight cvt (4352) + stats zero (1)
    prep<<<69889, 256, 0, stream>>>(x, w_in, w_emb, w_out, xT, wbin, wbemb, wbout, stats);

    // stage 1: conv1x1_in raw + fused stats
    gemm256<<<512, 512, 0, stream>>>(xT, wbin, y1, 1024, 512, stats);
    // gs descriptor (BN1+ReLU fused on staging; reads raw y1)
    selfcorr2<<<4096, 256, 0, stream>>>(y1, gs, stats, g1, b1);

    // stage 2: embeddingFea; A = BN1(y1)+ReLU (reg-staged) ++ gs (async tiles)
    gemm_reg<<<512, 512, 0, stream>>>(y1, gs, wbemb, h2, 640, 10, stats, g1, b1, stats + 1024);

    // stage 3: conv1x1_out; A = BN2(h2)+ReLU (reg-staged)
    gemm_reg<<<512, 512, 0, stream>>>(h2, gs, wbout, y3, 512, 8, stats + 1024, g2, b2, stats + 2048);

    // BN3 + transpose to NCHW fp32
    finalk<<<dim3(2048, 16), 256, 0, stream>>>(y3, stats + 2048, g3, b3, out);
}